// Round 8
// baseline (533.251 us; speedup 1.0000x reference)
//
#include <hip/hip_runtime.h>
#include <hip/hip_bf16.h>
#include <stdint.h>

#define D_MODEL 1024
#define NH 16
#define DK 64
#define S_LEN 2048

typedef __attribute__((ext_vector_type(8))) __bf16 bf16x8;
typedef __attribute__((ext_vector_type(4))) float f32x4;
typedef __attribute__((ext_vector_type(16))) float f32x16;

#define GLOBAL_AS __attribute__((address_space(1)))
#define LDS_AS    __attribute__((address_space(3)))

// async global->LDS DMA, 16B per lane; lane i's 16B lands at ldsbase + i*16.
__device__ __forceinline__ void async16(const ushort* g, ushort* l) {
    __builtin_amdgcn_global_load_lds(
        (const GLOBAL_AS uint32_t*)(uintptr_t)(const void*)g,
        (LDS_AS uint32_t*)(uint32_t)(uintptr_t)(void*)l,
        16, 0, 0);
}

// raw barrier with fine-grained vmcnt: waits until <=N VMEM ops outstanding.
template <int N>
__device__ __forceinline__ void pipe_barrier() {
    asm volatile("s_waitcnt vmcnt(%0)\n\ts_barrier" :: "n"(N) : "memory");
}

__device__ __forceinline__ float fast_exp2(float x) {
    float r;
    asm("v_exp_f32 %0, %1" : "=v"(r) : "v"(x));   // D = 2^S0
    return r;
}

// fp32 -> bf16 (RNE)
__device__ __forceinline__ ushort f2bf(float f) {
    union { float f; uint32_t u; } v; v.f = f;
    uint32_t lsb = (v.u >> 16) & 1u;
    return (ushort)((v.u + 0x7fffu + lsb) >> 16);
}

// two fp32 -> packed bf16x2 (round-half-up)
__device__ __forceinline__ uint32_t packbf(float a, float b) {
    union { float f; uint32_t u; } x, y; x.f = a; y.f = b;
    return ((x.u + 0x8000u) >> 16) | ((y.u + 0x8000u) & 0xffff0000u);
}

// two fp32 -> packed bf16x2 via native v_cvt_pk_bf16_f32 (RNE, 1 instr)
__device__ __forceinline__ uint32_t packbf_rn(float a, float b) {
    union { __hip_bfloat162 h; uint32_t u; } cv;
    cv.h = __float22bfloat162_rn(make_float2(a, b));
    return cv.u;
}

__device__ __forceinline__ bf16x8 ldfrag(const ushort* p) {
    union { uint4 u; bf16x8 b; } cv;
    cv.u = *(const uint4*)p;
    return cv.b;
}

// ---------------- fused convert kernel ----------------------------------------
// blocks [0,4096): x f32 -> bf16.  [4096,8192): 4 weight transposes (f32->bf16
// B^T).  [8192,8204): bias pack.  Parts are independent; branch is block-uniform.
__global__ void cvt_fused_kernel(
    const float* __restrict__ x, ushort* __restrict__ xb,
    const float* __restrict__ W0, const float* __restrict__ W1,
    const float* __restrict__ W2, const float* __restrict__ W3,
    ushort* __restrict__ D0, ushort* __restrict__ D1,
    ushort* __restrict__ D2, ushort* __restrict__ D3,
    const float* __restrict__ bq, const float* __restrict__ bk,
    const float* __restrict__ bv, float* __restrict__ biasq) {
    __shared__ float tile[32][33];
    const int bid = blockIdx.x, tid = threadIdx.x;
    if (bid < 4096) {
        int i = bid * 256 + tid;
        float4 v = ((const float4*)x)[i];
        ushort4 o;
        o.x = f2bf(v.x); o.y = f2bf(v.y); o.z = f2bf(v.z); o.w = f2bf(v.w);
        ((ushort4*)xb)[i] = o;
    } else if (bid < 8192) {
        int t = bid - 4096;
        int z = t >> 10, rem = t & 1023;
        const float* W; ushort* D;
        switch (z) {
            case 0: W = W0; D = D0; break;
            case 1: W = W1; D = D1; break;
            case 2: W = W2; D = D2; break;
            default: W = W3; D = D3; break;
        }
        int by = (rem >> 5) * 32, bx = (rem & 31) * 32;
        int tx = tid & 31, ty = tid >> 5;            // 32 x 8
#pragma unroll
        for (int j = 0; j < 32; j += 8)
            tile[ty + j][tx] = W[(size_t)(by + ty + j) * D_MODEL + bx + tx];
        __syncthreads();
#pragma unroll
        for (int j = 0; j < 32; j += 8)
            D[(size_t)(bx + ty + j) * D_MODEL + by + tx] = f2bf(tile[tx][ty + j]);
    } else {
        int i = (bid - 8192) * 256 + tid;            // 0..3071
        float v = (i < 1024) ? bq[i] : (i < 2048 ? bk[i - 1024] : bv[i - 2048]);
        biasq[i] = v;
    }
}

// ---------------- MFMA GEMM ---------------------------------------------------
// BK=32, THREE buffers (48/36 KB) -> 3 blocks/CU residency, single-generation
// grid. Stage issued at loop top; awaited stage is ~2 iterations old, covering
// HBM latency. Full unroll makes the %3 buffer rotation static.
// MODE 0: tile 128x128, grid 768, N-striped XCD. Each block is wholly Q, K or V.
// MODE 1: tile 128x64, grid 512, M-striped XCD; out = acc + bias + residual.
template <int MODE>
__global__ __launch_bounds__(256, 3) void gemm_kernel(
    const ushort* __restrict__ A, const ushort* __restrict__ Bt,
    const float* __restrict__ bias,
    ushort* __restrict__ outQ, ushort* __restrict__ outK, ushort* __restrict__ outVt,
    const float* __restrict__ xres, float* __restrict__ outF) {
    constexpr int BN = (MODE == 0) ? 128 : 64;
    constexpr int NI = (MODE == 0) ? 4 : 2;
    constexpr int NS = (MODE == 0) ? 4 : 3;        // per-wave DMA instrs / stage
    constexpr int ABUF = 4096;                     // ushorts per A buffer
    constexpr int BBUF = (MODE == 0) ? 4096 : 2048;
    constexpr int SMEM = (MODE == 0) ? 24576 : 18432;  // 48 / 36 KB
    __shared__ __align__(16) ushort smem[SMEM];
    ushort* sAb = smem;
    ushort* sBb = smem + 3 * ABUF;

    const int tid = threadIdx.x;
    const int wave = tid >> 6, lane = tid & 63;
    const int lr = lane & 15, lq = lane >> 4;
    const int srow = lane >> 3, sp = lane & 7;     // staging: 8 lanes / 128B row

    const int bid = blockIdx.x;
    const int xcd = bid & 7, lb = bid >> 3;
    int bx, by;
    if (MODE == 0) { bx = xcd * 3 + (lb % 3); by = lb / 3; }       // N-stripe
    else           { by = xcd * 4 + (lb & 3); bx = lb >> 2; }      // M-stripe
    const int blockM = by * 128;
    const int blockN = bx * BN;
    const int waveM = (wave >> 1) * 64;
    const int waveN = (MODE == 0) ? (wave & 1) * 64 : (wave & 1) * 32;

    // stage one BK=32 tile pair into buffer `buf`
    auto stage = [&](int k0, int buf) {
        ushort* a = sAb + buf * ABUF;
#pragma unroll
        for (int t = 0; t < 2; t++) {
            int Rb = wave * 16 + t * 8;            // uniform LDS row base
            int R = Rb + srow;
            int L = sp ^ (R & 7);
            int m = 2 * R + (L >> 2);
            int kc = L & 3;
            async16(&A[(size_t)(blockM + m) * D_MODEL + k0 + kc * 8], a + Rb * 64);
        }
        ushort* b = sBb + buf * BBUF;
        if (MODE == 0) {
#pragma unroll
            for (int t = 0; t < 2; t++) {
                int Rb = wave * 16 + t * 8;
                int R = Rb + srow;
                int L = sp ^ (R & 7);
                int n = 2 * R + (L >> 2);
                int kc = L & 3;
                async16(&Bt[(size_t)(blockN + n) * D_MODEL + k0 + kc * 8], b + Rb * 64);
            }
        } else {
            int Rb = wave * 8;
            int R = Rb + srow;
            int L = sp ^ (R & 7);
            int n = 2 * R + (L >> 2);
            int kc = L & 3;
            async16(&Bt[(size_t)(blockN + n) * D_MODEL + k0 + kc * 8], b + Rb * 64);
        }
    };

    // fragment read offsets (row-xor invariant across mi since rows step by 8)
    const int RA = (waveM >> 1) + (lr >> 1);
    const int offA = RA * 64 + ((((lr & 1) * 4 + lq) ^ (RA & 7)) * 8);
    const int RB = (waveN >> 1) + (lr >> 1);
    const int offB = RB * 64 + ((((lr & 1) * 4 + lq) ^ (RB & 7)) * 8);

    f32x4 acc[4][NI] = {};

    stage(0, 0);
    stage(32, 1);
    pipe_barrier<NS>();   // buf0 landed; buf1 in flight

#pragma unroll
    for (int k = 0; k < 32; k++) {
        const int buf = k % 3;
        if (k + 2 < 32) stage((k + 2) * 32, (k + 2) % 3);
        const ushort* a = sAb + buf * ABUF;
        const ushort* b = sBb + buf * BBUF;
        bf16x8 af[4], bfr[NI];
#pragma unroll
        for (int mi = 0; mi < 4; mi++)
            af[mi] = ldfrag(&a[offA + mi * 512]);
#pragma unroll
        for (int ni = 0; ni < NI; ni++)
            bfr[ni] = ldfrag(&b[offB + ni * 512]);
#pragma unroll
        for (int mi = 0; mi < 4; mi++)
#pragma unroll
            for (int ni = 0; ni < NI; ni++)
                acc[mi][ni] = __builtin_amdgcn_mfma_f32_16x16x32_bf16(
                    af[mi], bfr[ni], acc[mi][ni], 0, 0, 0);
        if (k < 30) pipe_barrier<NS>();           // awaited stage is ~2 iters old
        else if (k == 30) pipe_barrier<0>();
    }
    __syncthreads();   // all K-loop LDS reads done; smem now reused for epilogue

    const int bglob = blockM >> 11;
    const int sbase = blockM & 2047;

    if (MODE == 0) {
        const int which = bx >> 3;                // 0=Q 1=K 2=V, uniform per block
        if (which < 2) {
            // C -> LDS [m][n], stride 136, then coalesced [bh][s][d] stores
            const float scale = (which == 0) ? 0.1803368801f : 1.0f;  // 1/8*log2e
#pragma unroll
            for (int ni = 0; ni < 4; ni++) {
                const int n_loc = waveN + ni * 16 + lr;
                const float bn = bias[blockN + n_loc];
#pragma unroll
                for (int mi = 0; mi < 4; mi++)
#pragma unroll
                    for (int r = 0; r < 4; r++) {
                        int m_loc = waveM + mi * 16 + lq * 4 + r;
                        smem[m_loc * 136 + n_loc] =
                            f2bf((acc[mi][ni][r] + bn) * scale);
                    }
            }
            __syncthreads();
            ushort* outp = (which == 0) ? outQ : outK;
            const int hbase = (which == 0) ? bx * 2 : (bx - 8) * 2;
#pragma unroll
            for (int j = 0; j < 8; j++) {
                int c = tid + j * 256;            // 2048 chunks of 16B
                int m = c >> 4, nc = c & 15;
                int hh = nc >> 3, d8 = nc & 7;
                uint4 w = *(uint4*)&smem[m * 136 + nc * 8];
                size_t bh = (size_t)(bglob * NH + hbase + hh);
                *(uint4*)&outp[(bh * S_LEN + sbase + m) * DK + d8 * 8] = w;
            }
        } else {
            // V: C -> LDS [n][m] (b64 packed writes), then [bh][d][s] stores
#pragma unroll
            for (int ni = 0; ni < 4; ni++) {
                const int n_loc = waveN + ni * 16 + lr;
                const float bn = bias[blockN + n_loc];
#pragma unroll
                for (int mi = 0; mi < 4; mi++) {
                    uint2 w;
                    w.x = packbf(acc[mi][ni][0] + bn, acc[mi][ni][1] + bn);
                    w.y = packbf(acc[mi][ni][2] + bn, acc[mi][ni][3] + bn);
                    int m_base = waveM + mi * 16 + lq * 4;
                    *(uint2*)&smem[n_loc * 136 + m_base] = w;
                }
            }
            __syncthreads();
            const int hbase = (bx - 16) * 2;
#pragma unroll
            for (int j = 0; j < 8; j++) {
                int c = tid + j * 256;
                int n_loc = c >> 4, m8 = c & 15;
                int d = n_loc & 63, hh = n_loc >> 6;
                uint4 w = *(uint4*)&smem[n_loc * 136 + m8 * 8];
                size_t bh = (size_t)(bglob * NH + hbase + hh);
                *(uint4*)&outVt[(bh * DK + d) * S_LEN + sbase + m8 * 8] = w;
            }
        }
    } else {
        // fp32 out: C+bias -> LDS [m][n] stride 68, then +residual float4 stores
        float* sCf = (float*)smem;
#pragma unroll
        for (int ni = 0; ni < 2; ni++) {
            const int n_loc = waveN + ni * 16 + lr;
            const float bn = bias[blockN + n_loc];
#pragma unroll
            for (int mi = 0; mi < 4; mi++)
#pragma unroll
                for (int r = 0; r < 4; r++) {
                    int m_loc = waveM + mi * 16 + lq * 4 + r;
                    sCf[m_loc * 68 + n_loc] = acc[mi][ni][r] + bn;
                }
        }
        __syncthreads();
#pragma unroll
        for (int j = 0; j < 8; j++) {
            int c = tid + j * 256;               // 2048 chunks of 16B
            int m = c >> 4, nc = c & 15;
            float4 v = *(float4*)&sCf[m * 68 + nc * 4];
            size_t idx = (size_t)(blockM + m) * D_MODEL + blockN + nc * 4;
            float4 xr = *(const float4*)&xres[idx];
            v.x += xr.x; v.y += xr.y; v.z += xr.z; v.w += xr.w;
            *(float4*)&outF[idx] = v;
        }
    }
}

// ---------------- flash attention --------------------------------------------
// R13: structural change. QK and PV use mfma_f32_32x32x16_bf16; P never
// touches LDS. Key layout fact: the 32x32 C-layout (col=lane&31=q,
// row=(reg&3)+8*(reg>>2)+4*hi) and the PV B-operand layout (col=lane&31=q,
// k=hi*8+j) share the q=lane&31 assignment -- the k-redistribution is a pure
// lane<->lane+32 exchange = v_permlane32_swap_b32 (T12). Per 16-k window:
// 4 cvt_pk + 2 swaps build the PV fragment in-register, replacing the
// 8 ds_write_b64 + 4 ds_read_b128 P round-trip. ssum becomes a VALU partial
// sum per lane (each lane's 32 exps all belong to its own q) + one final
// permlane swap. LDS ops/iter: 28 -> 16. Staging schedule, buffers, vmcnt(4)
// barriers identical to the verified R7 kernel.
__global__ __launch_bounds__(256, 2) void attn_kernel(
    const ushort* __restrict__ Q, const ushort* __restrict__ Km,
    const ushort* __restrict__ Vt, ushort* __restrict__ ctx) {
    const int bid = blockIdx.x;
    const int xcd = bid & 7, lb = bid >> 3;
    const int bh = xcd * 4 + (lb & 3);
    const int qt = lb >> 2;
    const int q0 = qt * 128;
    __shared__ __align__(16) ushort sK[3][64 * 64];   // 24 KB
    __shared__ __align__(16) ushort sV[3][64 * 64];   // 24 KB
    __shared__ __align__(16) ushort sQP[4][32 * 64];  // 16 KB (Q only)
    const int tid = threadIdx.x;
    const int wave = tid >> 6, lane = tid & 63;
    const int l31 = lane & 31, hi = lane >> 5;
    const int srow = lane >> 3, sp = lane & 7;
    const ushort* Qh = Q + (size_t)bh * S_LEN * DK;
    const ushort* Kh = Km + (size_t)bh * S_LEN * DK;
    const ushort* Vh = Vt + (size_t)bh * DK * S_LEN;
    ushort* sPw = sQP[wave];

    // stage this wave's 32 Q rows (swizzled chunks, DMA-linear dest)
#pragma unroll
    for (int t = 0; t < 4; t++) {
        int row = t * 8 + srow;
        int c = sp ^ (row & 7);
        async16(&Qh[(size_t)(q0 + wave * 32 + row) * DK + c * 8],
                &sPw[t * 8 * 64]);
    }

    auto stageK = [&](int k0, int buf) {
#pragma unroll
        for (int t = 0; t < 2; t++) {
            int row = wave * 16 + t * 8 + srow;
            int c = sp ^ (row & 7);
            async16(&Kh[(size_t)(k0 + row) * DK + c * 8],
                    &sK[buf][(wave * 16 + t * 8) * 64]);
        }
    };
    auto stageV = [&](int k0, int buf) {
#pragma unroll
        for (int t = 0; t < 2; t++) {
            int row = wave * 16 + t * 8 + srow;
            int c = sp ^ (row & 7);
            async16(&Vh[(size_t)row * S_LEN + k0 + c * 8],
                    &sV[buf][(wave * 16 + t * 8) * 64]);
        }
    };

    // prologue stages: K(0..2), V(0..1)
    stageK(0, 0);
    stageV(0, 0);
    stageK(64, 1);
    stageV(64, 1);
    stageK(128, 2);
    __syncthreads();                     // drains all DMA (full vmcnt(0))

    // Q as B-operand: lane (hi,l31) holds Q[q=l31][dk=16*kk + 8*hi + j]
    bf16x8 qf[4];
#pragma unroll
    for (int kk = 0; kk < 4; kk++)
        qf[kk] = ldfrag(&sPw[l31 * 64 + (((2 * kk + hi) ^ (l31 & 7)) * 8)]);

    f32x16 cacc[2] = {};
    bf16x8 pfreg[4];
    float ssum_part = 0.0f;

    // S^T = K * Q^T (two 32x32 C-tiles, kv-rows mi*32+..): 8 MFMAs
    auto qk = [&](const ushort* sk, f32x16* sacc) {
#pragma unroll
        for (int kk = 0; kk < 4; kk++) {
            bf16x8 kf0 = ldfrag(&sk[l31 * 64 + (((2 * kk + hi) ^ (l31 & 7)) * 8)]);
            bf16x8 kf1 = ldfrag(&sk[(32 + l31) * 64 +
                                    (((2 * kk + hi) ^ (l31 & 7)) * 8)]);
            __builtin_amdgcn_s_setprio(1);
            sacc[0] = __builtin_amdgcn_mfma_f32_32x32x16_bf16(
                kf0, qf[kk], sacc[0], 0, 0, 0);
            sacc[1] = __builtin_amdgcn_mfma_f32_32x32x16_bf16(
                kf1, qf[kk], sacc[1], 0, 0, 0);
            __builtin_amdgcn_s_setprio(0);
        }
    };

    // P = exp2(S^T) -> bf16 PV fragments, fully in-register (permlane32_swap)
    auto expP = [&](f32x16* sacc) {
#pragma unroll
        for (int w = 0; w < 4; w++) {
            const int mi = w >> 1, r8 = (w & 1) * 8;
            float e0 = fast_exp2(sacc[mi][r8 + 0]);
            float e1 = fast_exp2(sacc[mi][r8 + 1]);
            float e2 = fast_exp2(sacc[mi][r8 + 2]);
            float e3 = fast_exp2(sacc[mi][r8 + 3]);
            float e4 = fast_exp2(sacc[mi][r8 + 4]);
            float e5 = fast_exp2(sacc[mi][r8 + 5]);
            float e6 = fast_exp2(sacc[mi][r8 + 6]);
            float e7 = fast_exp2(sacc[mi][r8 + 7]);
            ssum_part += ((e0 + e1) + (e2 + e3)) + ((e4 + e5) + (e6 + e7));
            uint32_t X0 = packbf_rn(e0, e1);
            uint32_t X1 = packbf_rn(e2, e3);
            uint32_t Y0 = packbf_rn(e4, e5);
            uint32_t Y1 = packbf_rn(e6, e7);
            // after swap: X = {X.lo, Y.lo} (j0,j1), Y = {X.hi, Y.hi} (j4,j5)
            asm("v_permlane32_swap_b32 %0, %1" : "+v"(X0), "+v"(Y0));
            asm("v_permlane32_swap_b32 %0, %1" : "+v"(X1), "+v"(Y1));
            union { uint4 u; bf16x8 b; } cv;
            cv.u = make_uint4(X0, X1, Y0, Y1);
            pfreg[w] = cv.b;
        }
    };

    // ctx^T += V^T * P : C[row=d][col=q], 8 MFMAs
    auto pv = [&](const ushort* sv) {
#pragma unroll
        for (int w = 0; w < 4; w++) {
            bf16x8 vf0 = ldfrag(&sv[l31 * 64 + (((2 * w + hi) ^ (l31 & 7)) * 8)]);
            bf16x8 vf1 = ldfrag(&sv[(32 + l31) * 64 +
                                    (((2 * w + hi) ^ (l31 & 7)) * 8)]);
            __builtin_amdgcn_s_setprio(1);
            cacc[0] = __builtin_amdgcn_mfma_f32_32x32x16_bf16(
                vf0, pfreg[w], cacc[0], 0, 0, 0);
            cacc[1] = __builtin_amdgcn_mfma_f32_32x32x16_bf16(
                vf1, pfreg[w], cacc[1], 0, 0, 0);
            __builtin_amdgcn_s_setprio(0);
        }
    };

    {   // prologue: QK(0) -> P(0)
        f32x16 s0[2] = {};
        qk(sK[0], s0);
        expP(s0);
    }
    // protect kb0 from iter-0's stageK(3) (3%3=0): all waves' prologue K0
    // reads are register-complete before each wave reaches this barrier.
    __builtin_amdgcn_s_barrier();

#pragma unroll 3
    for (int k = 0; k < 31; k++) {
        if (k + 3 < 32) stageK((k + 3) * 64, (k + 3) % 3);
        if (k + 2 < 32) stageV((k + 2) * 64, (k + 2) % 3);
        f32x16 s2[2] = {};
        qk(sK[(k + 1) % 3], s2);         // QK(k+1): staged 2 iters ago
        pv(sV[k % 3]);                   // PV(k): pfreg = P(k), V(k)
        if (k < 29) pipe_barrier<4>();   // this iter's 4 DMA stay in flight
        else if (k == 29) pipe_barrier<2>();
        else pipe_barrier<0>();
        expP(s2);                        // P(k+1) in regs; overlaps next QK
    }
    pv(sV[31 % 3]);                      // PV(31)

    // ssum: own partial + partner (lane^32) partial
    float spp = ssum_part, tpp = ssum_part;
    asm("v_permlane32_swap_b32 %0, %1" : "+v"(spp), "+v"(tpp));
    float partner = hi ? spp : tpp;
    float inv_q = __builtin_amdgcn_rcpf(ssum_part + partner);

    const int b = bh >> 4, h = bh & 15;
    const int qrow = q0 + wave * 32 + l31;
    ushort* orow = ctx + (size_t)(b * S_LEN + qrow) * D_MODEL + h * DK;
#pragma unroll
    for (int nd = 0; nd < 2; nd++)
#pragma unroll
        for (int t = 0; t < 4; t++) {
            uint2 wv;
            wv.x = packbf_rn(cacc[nd][4 * t + 0] * inv_q,
                             cacc[nd][4 * t + 1] * inv_q);
            wv.y = packbf_rn(cacc[nd][4 * t + 2] * inv_q,
                             cacc[nd][4 * t + 3] * inv_q);
            *(uint2*)&orow[nd * 32 + 8 * t + 4 * hi] = wv;
        }
}

// ---------------- launch ----------------

extern "C" void kernel_launch(void* const* d_in, const int* in_sizes, int n_in,
                              void* d_out, int out_size, void* d_ws, size_t ws_size,
                              hipStream_t stream) {
    const float* x  = (const float*)d_in[0];
    const float* Wq = (const float*)d_in[1];
    const float* bq = (const float*)d_in[2];
    const float* Wk = (const float*)d_in[3];
    const float* bk = (const float*)d_in[4];
    const float* Wv = (const float*)d_in[5];
    const float* bv = (const float*)d_in[6];
    const float* Wo = (const float*)d_in[7];
    const float* bo = (const float*)d_in[8];

    char* ws = (char*)d_ws;
    ushort* xb    = (ushort*)(ws);                        // 8 MB
    ushort* wqkv  = (ushort*)(ws + (8ull  << 20));        // 6 MB (B^T)
    ushort* wo_t  = (ushort*)(ws + (14ull << 20));        // 2 MB (B^T)
    ushort* qbuf  = (ushort*)(ws + (16ull << 20));        // 8 MB [32][2048][64]
    ushort* kbuf  = (ushort*)(ws + (24ull << 20));        // 8 MB [32][2048][64]
    ushort* vtb   = (ushort*)(ws + (32ull << 20));        // 8 MB [32][64][2048]
    ushort* ctx   = (ushort*)(ws + (40ull << 20));        // 8 MB [4096][1024]
    float*  biasq = (float*)(ws + (48ull << 20));         // 12 KB [3072]

    cvt_fused_kernel<<<8204, 256, 0, stream>>>(
        x, xb, Wq, Wk, Wv, Wo,
        wqkv, wqkv + 1024 * 1024, wqkv + 2 * 1024 * 1024, wo_t,
        bq, bk, bv, biasq);

    gemm_kernel<0><<<768, 256, 0, stream>>>(
        xb, wqkv, biasq, qbuf, kbuf, vtb, nullptr, nullptr);
    attn_kernel<<<512, 256, 0, stream>>>(qbuf, kbuf, vtb, ctx);
    gemm_kernel<1><<<512, 256, 0, stream>>>(
        ctx, wo_t, bo, nullptr, nullptr, nullptr, x, (float*)d_out);
}

// Round 9
// 193.510 us; speedup vs baseline: 2.7557x; 2.7557x over previous
//
#include <hip/hip_runtime.h>
#include <hip/hip_bf16.h>
#include <stdint.h>

#define D_MODEL 1024
#define NH 16
#define DK 64
#define S_LEN 2048

typedef __attribute__((ext_vector_type(8))) __bf16 bf16x8;
typedef __attribute__((ext_vector_type(4))) float f32x4;
typedef __attribute__((ext_vector_type(16))) float f32x16;

#define GLOBAL_AS __attribute__((address_space(1)))
#define LDS_AS    __attribute__((address_space(3)))

// async global->LDS DMA, 16B per lane; lane i's 16B lands at ldsbase + i*16.
__device__ __forceinline__ void async16(const ushort* g, ushort* l) {
    __builtin_amdgcn_global_load_lds(
        (const GLOBAL_AS uint32_t*)(uintptr_t)(const void*)g,
        (LDS_AS uint32_t*)(uint32_t)(uintptr_t)(void*)l,
        16, 0, 0);
}

// raw barrier with fine-grained vmcnt: waits until <=N VMEM ops outstanding.
template <int N>
__device__ __forceinline__ void pipe_barrier() {
    asm volatile("s_waitcnt vmcnt(%0)\n\ts_barrier" :: "n"(N) : "memory");
}

__device__ __forceinline__ float fast_exp2(float x) {
    float r;
    asm("v_exp_f32 %0, %1" : "=v"(r) : "v"(x));   // D = 2^S0
    return r;
}

// fp32 -> bf16 (RNE)
__device__ __forceinline__ ushort f2bf(float f) {
    union { float f; uint32_t u; } v; v.f = f;
    uint32_t lsb = (v.u >> 16) & 1u;
    return (ushort)((v.u + 0x7fffu + lsb) >> 16);
}

// two fp32 -> packed bf16x2 (round-half-up)
__device__ __forceinline__ uint32_t packbf(float a, float b) {
    union { float f; uint32_t u; } x, y; x.f = a; y.f = b;
    return ((x.u + 0x8000u) >> 16) | ((y.u + 0x8000u) & 0xffff0000u);
}

// two fp32 -> packed bf16x2 via native v_cvt_pk_bf16_f32 (RNE, 1 instr)
__device__ __forceinline__ uint32_t packbf_rn(float a, float b) {
    union { __hip_bfloat162 h; uint32_t u; } cv;
    cv.h = __float22bfloat162_rn(make_float2(a, b));
    return cv.u;
}

__device__ __forceinline__ bf16x8 ldfrag(const ushort* p) {
    union { uint4 u; bf16x8 b; } cv;
    cv.u = *(const uint4*)p;
    return cv.b;
}

// exp2 of 8 contiguous S^T values (regs BASE..BASE+7 of a 32x32 C tile) ->
// one PV bf16 A-fragment, fully in-register via 2x v_permlane32_swap.
// Takes the accumulator BY VALUE (SSA) -- no address-taken aggregates (R8
// lesson: pointer-passed f32x16 arrays across asm "memory" barriers go to
// scratch: 533MB WRITE_SIZE, 398us).
template <int BASE>
__device__ __forceinline__ bf16x8 exp_win(f32x16 s, float& ssum) {
    float e0 = fast_exp2(s[BASE + 0]);
    float e1 = fast_exp2(s[BASE + 1]);
    float e2 = fast_exp2(s[BASE + 2]);
    float e3 = fast_exp2(s[BASE + 3]);
    float e4 = fast_exp2(s[BASE + 4]);
    float e5 = fast_exp2(s[BASE + 5]);
    float e6 = fast_exp2(s[BASE + 6]);
    float e7 = fast_exp2(s[BASE + 7]);
    ssum += ((e0 + e1) + (e2 + e3)) + ((e4 + e5) + (e6 + e7));
    uint32_t X0 = packbf_rn(e0, e1);
    uint32_t X1 = packbf_rn(e2, e3);
    uint32_t Y0 = packbf_rn(e4, e5);
    uint32_t Y1 = packbf_rn(e6, e7);
    asm("v_permlane32_swap_b32 %0, %1" : "+v"(X0), "+v"(Y0));
    asm("v_permlane32_swap_b32 %0, %1" : "+v"(X1), "+v"(Y1));
    union { uint4 u; bf16x8 b; } cv;
    cv.u = make_uint4(X0, X1, Y0, Y1);
    return cv.b;
}

// ---------------- fused convert kernel ----------------------------------------
// blocks [0,4096): x f32 -> bf16.  [4096,8192): 4 weight transposes (f32->bf16
// B^T).  [8192,8204): bias pack.  Parts are independent; branch is block-uniform.
__global__ void cvt_fused_kernel(
    const float* __restrict__ x, ushort* __restrict__ xb,
    const float* __restrict__ W0, const float* __restrict__ W1,
    const float* __restrict__ W2, const float* __restrict__ W3,
    ushort* __restrict__ D0, ushort* __restrict__ D1,
    ushort* __restrict__ D2, ushort* __restrict__ D3,
    const float* __restrict__ bq, const float* __restrict__ bk,
    const float* __restrict__ bv, float* __restrict__ biasq) {
    __shared__ float tile[32][33];
    const int bid = blockIdx.x, tid = threadIdx.x;
    if (bid < 4096) {
        int i = bid * 256 + tid;
        float4 v = ((const float4*)x)[i];
        ushort4 o;
        o.x = f2bf(v.x); o.y = f2bf(v.y); o.z = f2bf(v.z); o.w = f2bf(v.w);
        ((ushort4*)xb)[i] = o;
    } else if (bid < 8192) {
        int t = bid - 4096;
        int z = t >> 10, rem = t & 1023;
        const float* W; ushort* D;
        switch (z) {
            case 0: W = W0; D = D0; break;
            case 1: W = W1; D = D1; break;
            case 2: W = W2; D = D2; break;
            default: W = W3; D = D3; break;
        }
        int by = (rem >> 5) * 32, bx = (rem & 31) * 32;
        int tx = tid & 31, ty = tid >> 5;            // 32 x 8
#pragma unroll
        for (int j = 0; j < 32; j += 8)
            tile[ty + j][tx] = W[(size_t)(by + ty + j) * D_MODEL + bx + tx];
        __syncthreads();
#pragma unroll
        for (int j = 0; j < 32; j += 8)
            D[(size_t)(bx + ty + j) * D_MODEL + by + tx] = f2bf(tile[tx][ty + j]);
    } else {
        int i = (bid - 8192) * 256 + tid;            // 0..3071
        float v = (i < 1024) ? bq[i] : (i < 2048 ? bk[i - 1024] : bv[i - 2048]);
        biasq[i] = v;
    }
}

// ---------------- MFMA GEMM ---------------------------------------------------
// BK=32, THREE buffers (48/36 KB) -> 3 blocks/CU residency, single-generation
// grid. Stage issued at loop top; awaited stage is ~2 iterations old, covering
// HBM latency. Full unroll makes the %3 buffer rotation static.
// MODE 0: tile 128x128, grid 768, N-striped XCD. Each block is wholly Q, K or V.
// MODE 1: tile 128x64, grid 512, M-striped XCD; out = acc + bias + residual.
template <int MODE>
__global__ __launch_bounds__(256, 3) void gemm_kernel(
    const ushort* __restrict__ A, const ushort* __restrict__ Bt,
    const float* __restrict__ bias,
    ushort* __restrict__ outQ, ushort* __restrict__ outK, ushort* __restrict__ outVt,
    const float* __restrict__ xres, float* __restrict__ outF) {
    constexpr int BN = (MODE == 0) ? 128 : 64;
    constexpr int NI = (MODE == 0) ? 4 : 2;
    constexpr int NS = (MODE == 0) ? 4 : 3;        // per-wave DMA instrs / stage
    constexpr int ABUF = 4096;                     // ushorts per A buffer
    constexpr int BBUF = (MODE == 0) ? 4096 : 2048;
    constexpr int SMEM = (MODE == 0) ? 24576 : 18432;  // 48 / 36 KB
    __shared__ __align__(16) ushort smem[SMEM];
    ushort* sAb = smem;
    ushort* sBb = smem + 3 * ABUF;

    const int tid = threadIdx.x;
    const int wave = tid >> 6, lane = tid & 63;
    const int lr = lane & 15, lq = lane >> 4;
    const int srow = lane >> 3, sp = lane & 7;     // staging: 8 lanes / 128B row

    const int bid = blockIdx.x;
    const int xcd = bid & 7, lb = bid >> 3;
    int bx, by;
    if (MODE == 0) { bx = xcd * 3 + (lb % 3); by = lb / 3; }       // N-stripe
    else           { by = xcd * 4 + (lb & 3); bx = lb >> 2; }      // M-stripe
    const int blockM = by * 128;
    const int blockN = bx * BN;
    const int waveM = (wave >> 1) * 64;
    const int waveN = (MODE == 0) ? (wave & 1) * 64 : (wave & 1) * 32;

    // stage one BK=32 tile pair into buffer `buf`
    auto stage = [&](int k0, int buf) {
        ushort* a = sAb + buf * ABUF;
#pragma unroll
        for (int t = 0; t < 2; t++) {
            int Rb = wave * 16 + t * 8;            // uniform LDS row base
            int R = Rb + srow;
            int L = sp ^ (R & 7);
            int m = 2 * R + (L >> 2);
            int kc = L & 3;
            async16(&A[(size_t)(blockM + m) * D_MODEL + k0 + kc * 8], a + Rb * 64);
        }
        ushort* b = sBb + buf * BBUF;
        if (MODE == 0) {
#pragma unroll
            for (int t = 0; t < 2; t++) {
                int Rb = wave * 16 + t * 8;
                int R = Rb + srow;
                int L = sp ^ (R & 7);
                int n = 2 * R + (L >> 2);
                int kc = L & 3;
                async16(&Bt[(size_t)(blockN + n) * D_MODEL + k0 + kc * 8], b + Rb * 64);
            }
        } else {
            int Rb = wave * 8;
            int R = Rb + srow;
            int L = sp ^ (R & 7);
            int n = 2 * R + (L >> 2);
            int kc = L & 3;
            async16(&Bt[(size_t)(blockN + n) * D_MODEL + k0 + kc * 8], b + Rb * 64);
        }
    };

    // fragment read offsets (row-xor invariant across mi since rows step by 8)
    const int RA = (waveM >> 1) + (lr >> 1);
    const int offA = RA * 64 + ((((lr & 1) * 4 + lq) ^ (RA & 7)) * 8);
    const int RB = (waveN >> 1) + (lr >> 1);
    const int offB = RB * 64 + ((((lr & 1) * 4 + lq) ^ (RB & 7)) * 8);

    f32x4 acc[4][NI] = {};

    stage(0, 0);
    stage(32, 1);
    pipe_barrier<NS>();   // buf0 landed; buf1 in flight

#pragma unroll
    for (int k = 0; k < 32; k++) {
        const int buf = k % 3;
        if (k + 2 < 32) stage((k + 2) * 32, (k + 2) % 3);
        const ushort* a = sAb + buf * ABUF;
        const ushort* b = sBb + buf * BBUF;
        bf16x8 af[4], bfr[NI];
#pragma unroll
        for (int mi = 0; mi < 4; mi++)
            af[mi] = ldfrag(&a[offA + mi * 512]);
#pragma unroll
        for (int ni = 0; ni < NI; ni++)
            bfr[ni] = ldfrag(&b[offB + ni * 512]);
#pragma unroll
        for (int mi = 0; mi < 4; mi++)
#pragma unroll
            for (int ni = 0; ni < NI; ni++)
                acc[mi][ni] = __builtin_amdgcn_mfma_f32_16x16x32_bf16(
                    af[mi], bfr[ni], acc[mi][ni], 0, 0, 0);
        if (k < 30) pipe_barrier<NS>();           // awaited stage is ~2 iters old
        else if (k == 30) pipe_barrier<0>();
    }
    __syncthreads();   // all K-loop LDS reads done; smem now reused for epilogue

    const int bglob = blockM >> 11;
    const int sbase = blockM & 2047;

    if (MODE == 0) {
        const int which = bx >> 3;                // 0=Q 1=K 2=V, uniform per block
        if (which < 2) {
            // C -> LDS [m][n], stride 136, then coalesced [bh][s][d] stores
            const float scale = (which == 0) ? 0.1803368801f : 1.0f;  // 1/8*log2e
#pragma unroll
            for (int ni = 0; ni < 4; ni++) {
                const int n_loc = waveN + ni * 16 + lr;
                const float bn = bias[blockN + n_loc];
#pragma unroll
                for (int mi = 0; mi < 4; mi++)
#pragma unroll
                    for (int r = 0; r < 4; r++) {
                        int m_loc = waveM + mi * 16 + lq * 4 + r;
                        smem[m_loc * 136 + n_loc] =
                            f2bf((acc[mi][ni][r] + bn) * scale);
                    }
            }
            __syncthreads();
            ushort* outp = (which == 0) ? outQ : outK;
            const int hbase = (which == 0) ? bx * 2 : (bx - 8) * 2;
#pragma unroll
            for (int j = 0; j < 8; j++) {
                int c = tid + j * 256;            // 2048 chunks of 16B
                int m = c >> 4, nc = c & 15;
                int hh = nc >> 3, d8 = nc & 7;
                uint4 w = *(uint4*)&smem[m * 136 + nc * 8];
                size_t bh = (size_t)(bglob * NH + hbase + hh);
                *(uint4*)&outp[(bh * S_LEN + sbase + m) * DK + d8 * 8] = w;
            }
        } else {
            // V: C -> LDS [n][m] (b64 packed writes), then [bh][d][s] stores
#pragma unroll
            for (int ni = 0; ni < 4; ni++) {
                const int n_loc = waveN + ni * 16 + lr;
                const float bn = bias[blockN + n_loc];
#pragma unroll
                for (int mi = 0; mi < 4; mi++) {
                    uint2 w;
                    w.x = packbf(acc[mi][ni][0] + bn, acc[mi][ni][1] + bn);
                    w.y = packbf(acc[mi][ni][2] + bn, acc[mi][ni][3] + bn);
                    int m_base = waveM + mi * 16 + lq * 4;
                    *(uint2*)&smem[n_loc * 136 + m_base] = w;
                }
            }
            __syncthreads();
            const int hbase = (bx - 16) * 2;
#pragma unroll
            for (int j = 0; j < 8; j++) {
                int c = tid + j * 256;
                int n_loc = c >> 4, m8 = c & 15;
                int d = n_loc & 63, hh = n_loc >> 6;
                uint4 w = *(uint4*)&smem[n_loc * 136 + m8 * 8];
                size_t bh = (size_t)(bglob * NH + hbase + hh);
                *(uint4*)&outVt[(bh * DK + d) * S_LEN + sbase + m8 * 8] = w;
            }
        }
    } else {
        // fp32 out: C+bias -> LDS [m][n] stride 68, then +residual float4 stores
        float* sCf = (float*)smem;
#pragma unroll
        for (int ni = 0; ni < 2; ni++) {
            const int n_loc = waveN + ni * 16 + lr;
            const float bn = bias[blockN + n_loc];
#pragma unroll
            for (int mi = 0; mi < 4; mi++)
#pragma unroll
                for (int r = 0; r < 4; r++) {
                    int m_loc = waveM + mi * 16 + lq * 4 + r;
                    sCf[m_loc * 68 + n_loc] = acc[mi][ni][r] + bn;
                }
        }
        __syncthreads();
#pragma unroll
        for (int j = 0; j < 8; j++) {
            int c = tid + j * 256;               // 2048 chunks of 16B
            int m = c >> 4, nc = c & 15;
            float4 v = *(float4*)&sCf[m * 68 + nc * 4];
            size_t idx = (size_t)(blockM + m) * D_MODEL + blockN + nc * 4;
            float4 xr = *(const float4*)&xres[idx];
            v.x += xr.x; v.y += xr.y; v.z += xr.z; v.w += xr.w;
            *(float4*)&outF[idx] = v;
        }
    }
}

// ---------------- flash attention --------------------------------------------
// R14 = R13's verified-correct 32x32 algorithm with register hygiene:
// all accumulators are NAMED f32x16 SSA values (cacc0/cacc1, sa/sb), QK/PV
// bodies inlined in the loop, exp window is a by-value template helper,
// buffer rotation via rotating pointers. No address-taken aggregates ->
// nothing can be forced to scratch by the barrier's "memory" clobber.
// Schedule identical to R7/R12: K dist-3, V dist-2, vmcnt(4) barriers.
__global__ __launch_bounds__(256, 2) void attn_kernel(
    const ushort* __restrict__ Q, const ushort* __restrict__ Km,
    const ushort* __restrict__ Vt, ushort* __restrict__ ctx) {
    const int bid = blockIdx.x;
    const int xcd = bid & 7, lb = bid >> 3;
    const int bh = xcd * 4 + (lb & 3);
    const int qt = lb >> 2;
    const int q0 = qt * 128;
    __shared__ __align__(16) ushort sK[3][64 * 64];   // 24 KB
    __shared__ __align__(16) ushort sV[3][64 * 64];   // 24 KB
    __shared__ __align__(16) ushort sQP[4][32 * 64];  // 16 KB (Q only)
    const int tid = threadIdx.x;
    const int wave = tid >> 6, lane = tid & 63;
    const int l31 = lane & 31, hi = lane >> 5;
    const int srow = lane >> 3, sp = lane & 7;
    const ushort* Qh = Q + (size_t)bh * S_LEN * DK;
    const ushort* Kh = Km + (size_t)bh * S_LEN * DK;
    const ushort* Vh = Vt + (size_t)bh * DK * S_LEN;
    ushort* sPw = sQP[wave];

    // stage this wave's 32 Q rows (swizzled chunks, DMA-linear dest)
#pragma unroll
    for (int t = 0; t < 4; t++) {
        int row = t * 8 + srow;
        int c = sp ^ (row & 7);
        async16(&Qh[(size_t)(q0 + wave * 32 + row) * DK + c * 8],
                &sPw[t * 8 * 64]);
    }

    auto stageK = [&](int k0, ushort* dst) {
#pragma unroll
        for (int t = 0; t < 2; t++) {
            int row = wave * 16 + t * 8 + srow;
            int c = sp ^ (row & 7);
            async16(&Kh[(size_t)(k0 + row) * DK + c * 8],
                    dst + (wave * 16 + t * 8) * 64);
        }
    };
    auto stageV = [&](int k0, ushort* dst) {
#pragma unroll
        for (int t = 0; t < 2; t++) {
            int row = wave * 16 + t * 8 + srow;
            int c = sp ^ (row & 7);
            async16(&Vh[(size_t)row * S_LEN + k0 + c * 8],
                    dst + (wave * 16 + t * 8) * 64);
        }
    };

    // prologue stages: K(0..2), V(0..1)
    stageK(0, sK[0]);
    stageV(0, sV[0]);
    stageK(64, sK[1]);
    stageV(64, sV[1]);
    stageK(128, sK[2]);
    __syncthreads();                     // drains all DMA (full vmcnt(0))

    // Q as B-operand: lane (hi,l31) holds Q[q=l31][dk=16*kk + 8*hi + j]
    bf16x8 qf0 = ldfrag(&sPw[l31 * 64 + (((0 + hi) ^ (l31 & 7)) * 8)]);
    bf16x8 qf1 = ldfrag(&sPw[l31 * 64 + (((2 + hi) ^ (l31 & 7)) * 8)]);
    bf16x8 qf2 = ldfrag(&sPw[l31 * 64 + (((4 + hi) ^ (l31 & 7)) * 8)]);
    bf16x8 qf3 = ldfrag(&sPw[l31 * 64 + (((6 + hi) ^ (l31 & 7)) * 8)]);

    f32x16 cacc0 = {}, cacc1 = {};
    bf16x8 pf0, pf1, pf2, pf3;
    float ssum_part = 0.0f;

    // one QK K=16 step on both 32-row halves of a K-tile
#define QK_STEP(sk, KK, QF, A0, A1)                                            \
    {                                                                          \
        bf16x8 kf0_ = ldfrag(&(sk)[l31 * 64 + (((2 * KK + hi) ^ (l31 & 7)) * 8)]); \
        bf16x8 kf1_ = ldfrag(&(sk)[(32 + l31) * 64 +                           \
                                   (((2 * KK + hi) ^ (l31 & 7)) * 8)]);        \
        __builtin_amdgcn_s_setprio(1);                                         \
        A0 = __builtin_amdgcn_mfma_f32_32x32x16_bf16(kf0_, QF, A0, 0, 0, 0);   \
        A1 = __builtin_amdgcn_mfma_f32_32x32x16_bf16(kf1_, QF, A1, 0, 0, 0);   \
        __builtin_amdgcn_s_setprio(0);                                         \
    }

#define QK_TILE(sk, A0, A1)                                                    \
    QK_STEP(sk, 0, qf0, A0, A1)                                                \
    QK_STEP(sk, 1, qf1, A0, A1)                                                \
    QK_STEP(sk, 2, qf2, A0, A1)                                                \
    QK_STEP(sk, 3, qf3, A0, A1)

#define EXP_ALL(A0, A1)                                                        \
    pf0 = exp_win<0>(A0, ssum_part);                                           \
    pf1 = exp_win<8>(A0, ssum_part);                                           \
    pf2 = exp_win<0>(A1, ssum_part);                                           \
    pf3 = exp_win<8>(A1, ssum_part);

#define PV_STEP(sv, W, PW)                                                     \
    {                                                                          \
        bf16x8 vf0_ = ldfrag(&(sv)[l31 * 64 + (((2 * W + hi) ^ (l31 & 7)) * 8)]); \
        bf16x8 vf1_ = ldfrag(&(sv)[(32 + l31) * 64 +                           \
                                   (((2 * W + hi) ^ (l31 & 7)) * 8)]);         \
        __builtin_amdgcn_s_setprio(1);                                         \
        cacc0 = __builtin_amdgcn_mfma_f32_32x32x16_bf16(vf0_, PW, cacc0, 0, 0, 0); \
        cacc1 = __builtin_amdgcn_mfma_f32_32x32x16_bf16(vf1_, PW, cacc1, 0, 0, 0); \
        __builtin_amdgcn_s_setprio(0);                                         \
    }

#define PV_TILE(sv)                                                            \
    PV_STEP(sv, 0, pf0)                                                        \
    PV_STEP(sv, 1, pf1)                                                        \
    PV_STEP(sv, 2, pf2)                                                        \
    PV_STEP(sv, 3, pf3)

    {   // prologue: QK(0) -> P(0) fragments
        f32x16 sa = {}, sb = {};
        QK_TILE(sK[0], sa, sb)
        EXP_ALL(sa, sb)
    }
    // protect sK[0] from iter-0's stageK(3): all waves' prologue K0 reads are
    // register-complete before each wave reaches this barrier.
    __builtin_amdgcn_s_barrier();

    // rotating buffer pointers: kA = (k)%3 [stage K(k+3)], kB = (k+1)%3 [read],
    // vA = (k)%3 [read V(k)], vC = (k+2)%3 [stage V(k+2)]
    ushort *kA = sK[0], *kB = sK[1], *kC = sK[2];
    ushort *vA = sV[0], *vB = sV[1], *vC = sV[2];

    for (int k = 0; k < 31; k++) {
        if (k + 3 < 32) stageK((k + 3) * 64, kA);
        if (k + 2 < 32) stageV((k + 2) * 64, vC);
        f32x16 sa = {}, sb = {};
        QK_TILE(kB, sa, sb)              // QK(k+1): staged 2 iters ago
        PV_TILE(vA)                      // PV(k): pf* = P(k), V(k)
        if (k < 29) pipe_barrier<4>();   // this iter's 4 DMA stay in flight
        else if (k == 29) pipe_barrier<2>();
        else pipe_barrier<0>();
        EXP_ALL(sa, sb)                  // P(k+1) in regs; overlaps next QK
        ushort* t;
        t = kA; kA = kB; kB = kC; kC = t;
        t = vA; vA = vB; vB = vC; vC = t;
    }
    PV_TILE(vA)                          // PV(31): vA = sV[31%3]

    // ssum: own partial + partner (lane^32) partial
    float spp = ssum_part, tpp = ssum_part;
    asm("v_permlane32_swap_b32 %0, %1" : "+v"(spp), "+v"(tpp));
    float partner = hi ? spp : tpp;
    float inv_q = __builtin_amdgcn_rcpf(ssum_part + partner);

    const int b = bh >> 4, h = bh & 15;
    const int qrow = q0 + wave * 32 + l31;
    ushort* orow = ctx + (size_t)(b * S_LEN + qrow) * D_MODEL + h * DK;
#pragma unroll
    for (int t = 0; t < 4; t++) {
        uint2 wv;
        wv.x = packbf_rn(cacc0[4 * t + 0] * inv_q, cacc0[4 * t + 1] * inv_q);
        wv.y = packbf_rn(cacc0[4 * t + 2] * inv_q, cacc0[4 * t + 3] * inv_q);
        *(uint2*)&orow[8 * t + 4 * hi] = wv;
    }
#pragma unroll
    for (int t = 0; t < 4; t++) {
        uint2 wv;
        wv.x = packbf_rn(cacc1[4 * t + 0] * inv_q, cacc1[4 * t + 1] * inv_q);
        wv.y = packbf_rn(cacc1[4 * t + 2] * inv_q, cacc1[4 * t + 3] * inv_q);
        *(uint2*)&orow[32 + 8 * t + 4 * hi] = wv;
    }
#undef QK_STEP
#undef QK_TILE
#undef EXP_ALL
#undef PV_STEP
#undef PV_TILE
}

// ---------------- launch ----------------

extern "C" void kernel_launch(void* const* d_in, const int* in_sizes, int n_in,
                              void* d_out, int out_size, void* d_ws, size_t ws_size,
                              hipStream_t stream) {
    const float* x  = (const float*)d_in[0];
    const float* Wq = (const float*)d_in[1];
    const float* bq = (const float*)d_in[2];
    const float* Wk = (const float*)d_in[3];
    const float* bk = (const float*)d_in[4];
    const float* Wv = (const float*)d_in[5];
    const float* bv = (const float*)d_in[6];
    const float* Wo = (const float*)d_in[7];
    const float* bo = (const float*)d_in[8];

    char* ws = (char*)d_ws;
    ushort* xb    = (ushort*)(ws);                        // 8 MB
    ushort* wqkv  = (ushort*)(ws + (8ull  << 20));        // 6 MB (B^T)
    ushort* wo_t  = (ushort*)(ws + (14ull << 20));        // 2 MB (B^T)
    ushort* qbuf  = (ushort*)(ws + (16ull << 20));        // 8 MB [32][2048][64]
    ushort* kbuf  = (ushort*)(ws + (24ull << 20));        // 8 MB [32][2048][64]
    ushort* vtb   = (ushort*)(ws + (32ull << 20));        // 8 MB [32][64][2048]
    ushort* ctx   = (ushort*)(ws + (40ull << 20));        // 8 MB [4096][1024]
    float*  biasq = (float*)(ws + (48ull << 20));         // 12 KB [3072]

    cvt_fused_kernel<<<8204, 256, 0, stream>>>(
        x, xb, Wq, Wk, Wv, Wo,
        wqkv, wqkv + 1024 * 1024, wqkv + 2 * 1024 * 1024, wo_t,
        bq, bk, bv, biasq);

    gemm_kernel<0><<<768, 256, 0, stream>>>(
        xb, wqkv, biasq, qbuf, kbuf, vtb, nullptr, nullptr);
    attn_kernel<<<512, 256, 0, stream>>>(qbuf, kbuf, vtb, ctx);
    gemm_kernel<1><<<512, 256, 0, stream>>>(
        ctx, wo_t, bo, nullptr, nullptr, nullptr, x, (float*)d_out);
}

// Round 10
// 187.069 us; speedup vs baseline: 2.8506x; 1.0344x over previous
//
#include <hip/hip_runtime.h>
#include <hip/hip_bf16.h>
#include <stdint.h>

#define D_MODEL 1024
#define NH 16
#define DK 64
#define S_LEN 2048

typedef __attribute__((ext_vector_type(8))) __bf16 bf16x8;
typedef __attribute__((ext_vector_type(4))) float f32x4;

#define GLOBAL_AS __attribute__((address_space(1)))
#define LDS_AS    __attribute__((address_space(3)))

// async global->LDS DMA, 16B per lane; lane i's 16B lands at ldsbase + i*16.
__device__ __forceinline__ void async16(const ushort* g, ushort* l) {
    __builtin_amdgcn_global_load_lds(
        (const GLOBAL_AS uint32_t*)(uintptr_t)(const void*)g,
        (LDS_AS uint32_t*)(uint32_t)(uintptr_t)(void*)l,
        16, 0, 0);
}

// raw barrier with fine-grained vmcnt: waits until <=N VMEM ops outstanding.
template <int N>
__device__ __forceinline__ void pipe_barrier() {
    asm volatile("s_waitcnt vmcnt(%0)\n\ts_barrier" :: "n"(N) : "memory");
}

__device__ __forceinline__ float fast_exp2(float x) {
    float r;
    asm("v_exp_f32 %0, %1" : "=v"(r) : "v"(x));   // D = 2^S0
    return r;
}

// fp32 -> bf16 (RNE)
__device__ __forceinline__ ushort f2bf(float f) {
    union { float f; uint32_t u; } v; v.f = f;
    uint32_t lsb = (v.u >> 16) & 1u;
    return (ushort)((v.u + 0x7fffu + lsb) >> 16);
}

// two fp32 -> packed bf16x2 (round-half-up)
__device__ __forceinline__ uint32_t packbf(float a, float b) {
    union { float f; uint32_t u; } x, y; x.f = a; y.f = b;
    return ((x.u + 0x8000u) >> 16) | ((y.u + 0x8000u) & 0xffff0000u);
}

// two fp32 -> packed bf16x2 via native v_cvt_pk_bf16_f32 (RNE, 1 instr)
__device__ __forceinline__ uint32_t packbf_rn(float a, float b) {
    union { __hip_bfloat162 h; uint32_t u; } cv;
    cv.h = __float22bfloat162_rn(make_float2(a, b));
    return cv.u;
}

__device__ __forceinline__ bf16x8 ldfrag(const ushort* p) {
    union { uint4 u; bf16x8 b; } cv;
    cv.u = *(const uint4*)p;
    return cv.b;
}

// ---------------- fused convert kernel ----------------------------------------
// blocks [0,4096): x f32 -> bf16.  [4096,8192): 4 weight transposes (f32->bf16
// B^T).  [8192,8204): bias pack.  Parts are independent; branch is block-uniform.
__global__ void cvt_fused_kernel(
    const float* __restrict__ x, ushort* __restrict__ xb,
    const float* __restrict__ W0, const float* __restrict__ W1,
    const float* __restrict__ W2, const float* __restrict__ W3,
    ushort* __restrict__ D0, ushort* __restrict__ D1,
    ushort* __restrict__ D2, ushort* __restrict__ D3,
    const float* __restrict__ bq, const float* __restrict__ bk,
    const float* __restrict__ bv, float* __restrict__ biasq) {
    __shared__ float tile[32][33];
    const int bid = blockIdx.x, tid = threadIdx.x;
    if (bid < 4096) {
        int i = bid * 256 + tid;
        float4 v = ((const float4*)x)[i];
        ushort4 o;
        o.x = f2bf(v.x); o.y = f2bf(v.y); o.z = f2bf(v.z); o.w = f2bf(v.w);
        ((ushort4*)xb)[i] = o;
    } else if (bid < 8192) {
        int t = bid - 4096;
        int z = t >> 10, rem = t & 1023;
        const float* W; ushort* D;
        switch (z) {
            case 0: W = W0; D = D0; break;
            case 1: W = W1; D = D1; break;
            case 2: W = W2; D = D2; break;
            default: W = W3; D = D3; break;
        }
        int by = (rem >> 5) * 32, bx = (rem & 31) * 32;
        int tx = tid & 31, ty = tid >> 5;            // 32 x 8
#pragma unroll
        for (int j = 0; j < 32; j += 8)
            tile[ty + j][tx] = W[(size_t)(by + ty + j) * D_MODEL + bx + tx];
        __syncthreads();
#pragma unroll
        for (int j = 0; j < 32; j += 8)
            D[(size_t)(bx + ty + j) * D_MODEL + by + tx] = f2bf(tile[tx][ty + j]);
    } else {
        int i = (bid - 8192) * 256 + tid;            // 0..3071
        float v = (i < 1024) ? bq[i] : (i < 2048 ? bk[i - 1024] : bv[i - 2048]);
        biasq[i] = v;
    }
}

// ---------------- MFMA GEMM ---------------------------------------------------
// BK=32, THREE buffers (48/36 KB) -> 3 blocks/CU residency, single-generation
// grid. Stage issued at loop top; awaited stage is ~2 iterations old, covering
// HBM latency. Full unroll makes the %3 buffer rotation static.
// MODE 0: tile 128x128, grid 768, N-striped XCD. Each block is wholly Q, K or V.
// MODE 1: tile 128x64, grid 512, M-striped XCD; out = acc + bias + residual.
template <int MODE>
__global__ __launch_bounds__(256, 3) void gemm_kernel(
    const ushort* __restrict__ A, const ushort* __restrict__ Bt,
    const float* __restrict__ bias,
    ushort* __restrict__ outQ, ushort* __restrict__ outK, ushort* __restrict__ outVt,
    const float* __restrict__ xres, float* __restrict__ outF) {
    constexpr int BN = (MODE == 0) ? 128 : 64;
    constexpr int NI = (MODE == 0) ? 4 : 2;
    constexpr int NS = (MODE == 0) ? 4 : 3;        // per-wave DMA instrs / stage
    constexpr int ABUF = 4096;                     // ushorts per A buffer
    constexpr int BBUF = (MODE == 0) ? 4096 : 2048;
    constexpr int SMEM = (MODE == 0) ? 24576 : 18432;  // 48 / 36 KB
    __shared__ __align__(16) ushort smem[SMEM];
    ushort* sAb = smem;
    ushort* sBb = smem + 3 * ABUF;

    const int tid = threadIdx.x;
    const int wave = tid >> 6, lane = tid & 63;
    const int lr = lane & 15, lq = lane >> 4;
    const int srow = lane >> 3, sp = lane & 7;     // staging: 8 lanes / 128B row

    const int bid = blockIdx.x;
    const int xcd = bid & 7, lb = bid >> 3;
    int bx, by;
    if (MODE == 0) { bx = xcd * 3 + (lb % 3); by = lb / 3; }       // N-stripe
    else           { by = xcd * 4 + (lb & 3); bx = lb >> 2; }      // M-stripe
    const int blockM = by * 128;
    const int blockN = bx * BN;
    const int waveM = (wave >> 1) * 64;
    const int waveN = (MODE == 0) ? (wave & 1) * 64 : (wave & 1) * 32;

    // stage one BK=32 tile pair into buffer `buf`
    auto stage = [&](int k0, int buf) {
        ushort* a = sAb + buf * ABUF;
#pragma unroll
        for (int t = 0; t < 2; t++) {
            int Rb = wave * 16 + t * 8;            // uniform LDS row base
            int R = Rb + srow;
            int L = sp ^ (R & 7);
            int m = 2 * R + (L >> 2);
            int kc = L & 3;
            async16(&A[(size_t)(blockM + m) * D_MODEL + k0 + kc * 8], a + Rb * 64);
        }
        ushort* b = sBb + buf * BBUF;
        if (MODE == 0) {
#pragma unroll
            for (int t = 0; t < 2; t++) {
                int Rb = wave * 16 + t * 8;
                int R = Rb + srow;
                int L = sp ^ (R & 7);
                int n = 2 * R + (L >> 2);
                int kc = L & 3;
                async16(&Bt[(size_t)(blockN + n) * D_MODEL + k0 + kc * 8], b + Rb * 64);
            }
        } else {
            int Rb = wave * 8;
            int R = Rb + srow;
            int L = sp ^ (R & 7);
            int n = 2 * R + (L >> 2);
            int kc = L & 3;
            async16(&Bt[(size_t)(blockN + n) * D_MODEL + k0 + kc * 8], b + Rb * 64);
        }
    };

    // fragment read offsets (row-xor invariant across mi since rows step by 8)
    const int RA = (waveM >> 1) + (lr >> 1);
    const int offA = RA * 64 + ((((lr & 1) * 4 + lq) ^ (RA & 7)) * 8);
    const int RB = (waveN >> 1) + (lr >> 1);
    const int offB = RB * 64 + ((((lr & 1) * 4 + lq) ^ (RB & 7)) * 8);

    f32x4 acc[4][NI] = {};

    stage(0, 0);
    stage(32, 1);
    pipe_barrier<NS>();   // buf0 landed; buf1 in flight

#pragma unroll
    for (int k = 0; k < 32; k++) {
        const int buf = k % 3;
        if (k + 2 < 32) stage((k + 2) * 32, (k + 2) % 3);
        const ushort* a = sAb + buf * ABUF;
        const ushort* b = sBb + buf * BBUF;
        bf16x8 af[4], bfr[NI];
#pragma unroll
        for (int mi = 0; mi < 4; mi++)
            af[mi] = ldfrag(&a[offA + mi * 512]);
#pragma unroll
        for (int ni = 0; ni < NI; ni++)
            bfr[ni] = ldfrag(&b[offB + ni * 512]);
#pragma unroll
        for (int mi = 0; mi < 4; mi++)
#pragma unroll
            for (int ni = 0; ni < NI; ni++)
                acc[mi][ni] = __builtin_amdgcn_mfma_f32_16x16x32_bf16(
                    af[mi], bfr[ni], acc[mi][ni], 0, 0, 0);
        if (k < 30) pipe_barrier<NS>();           // awaited stage is ~2 iters old
        else if (k == 30) pipe_barrier<0>();
    }
    __syncthreads();   // all K-loop LDS reads done; smem now reused for epilogue

    const int bglob = blockM >> 11;
    const int sbase = blockM & 2047;

    if (MODE == 0) {
        const int which = bx >> 3;                // 0=Q 1=K 2=V, uniform per block
        if (which < 2) {
            // C -> LDS [m][n], stride 136, then coalesced [bh][s][d] stores
            const float scale = (which == 0) ? 0.1803368801f : 1.0f;  // 1/8*log2e
#pragma unroll
            for (int ni = 0; ni < 4; ni++) {
                const int n_loc = waveN + ni * 16 + lr;
                const float bn = bias[blockN + n_loc];
#pragma unroll
                for (int mi = 0; mi < 4; mi++)
#pragma unroll
                    for (int r = 0; r < 4; r++) {
                        int m_loc = waveM + mi * 16 + lq * 4 + r;
                        smem[m_loc * 136 + n_loc] =
                            f2bf((acc[mi][ni][r] + bn) * scale);
                    }
            }
            __syncthreads();
            ushort* outp = (which == 0) ? outQ : outK;
            const int hbase = (which == 0) ? bx * 2 : (bx - 8) * 2;
#pragma unroll
            for (int j = 0; j < 8; j++) {
                int c = tid + j * 256;            // 2048 chunks of 16B
                int m = c >> 4, nc = c & 15;
                int hh = nc >> 3, d8 = nc & 7;
                uint4 w = *(uint4*)&smem[m * 136 + nc * 8];
                size_t bh = (size_t)(bglob * NH + hbase + hh);
                *(uint4*)&outp[(bh * S_LEN + sbase + m) * DK + d8 * 8] = w;
            }
        } else {
            // V: C -> LDS [n][m] (b64 packed writes), then [bh][d][s] stores
#pragma unroll
            for (int ni = 0; ni < 4; ni++) {
                const int n_loc = waveN + ni * 16 + lr;
                const float bn = bias[blockN + n_loc];
#pragma unroll
                for (int mi = 0; mi < 4; mi++) {
                    uint2 w;
                    w.x = packbf(acc[mi][ni][0] + bn, acc[mi][ni][1] + bn);
                    w.y = packbf(acc[mi][ni][2] + bn, acc[mi][ni][3] + bn);
                    int m_base = waveM + mi * 16 + lq * 4;
                    *(uint2*)&smem[n_loc * 136 + m_base] = w;
                }
            }
            __syncthreads();
            const int hbase = (bx - 16) * 2;
#pragma unroll
            for (int j = 0; j < 8; j++) {
                int c = tid + j * 256;
                int n_loc = c >> 4, m8 = c & 15;
                int d = n_loc & 63, hh = n_loc >> 6;
                uint4 w = *(uint4*)&smem[n_loc * 136 + m8 * 8];
                size_t bh = (size_t)(bglob * NH + hbase + hh);
                *(uint4*)&outVt[(bh * DK + d) * S_LEN + sbase + m8 * 8] = w;
            }
        }
    } else {
        // fp32 out: C+bias -> LDS [m][n] stride 68, then +residual float4 stores
        float* sCf = (float*)smem;
#pragma unroll
        for (int ni = 0; ni < 2; ni++) {
            const int n_loc = waveN + ni * 16 + lr;
            const float bn = bias[blockN + n_loc];
#pragma unroll
            for (int mi = 0; mi < 4; mi++)
#pragma unroll
                for (int r = 0; r < 4; r++) {
                    int m_loc = waveM + mi * 16 + lq * 4 + r;
                    sCf[m_loc * 68 + n_loc] = acc[mi][ni][r] + bn;
                }
        }
        __syncthreads();
#pragma unroll
        for (int j = 0; j < 8; j++) {
            int c = tid + j * 256;               // 2048 chunks of 16B
            int m = c >> 4, nc = c & 15;
            float4 v = *(float4*)&sCf[m * 68 + nc * 4];
            size_t idx = (size_t)(blockM + m) * D_MODEL + blockN + nc * 4;
            float4 xr = *(const float4*)&xres[idx];
            v.x += xr.x; v.y += xr.y; v.z += xr.z; v.w += xr.w;
            *(float4*)&outF[idx] = v;
        }
    }
}

// ---------------- flash attention --------------------------------------------
// R15 = R7's verified 16x16 kernel (46.2us) with the P LDS round-trip
// (8 ds_write_b64 + 4 ds_read_b128 per wave-iter) replaced by an in-register
// permlane redistribution. Derivation: QK's S^T gives lane (lr,lq) the values
// P[q=lr (+16nj)][k=mi*16+lq*4+r]; PV's A-fragment needs lane (lr,lq) to hold
// P[q][k=32ks+8lq+j]. Source lane = (lr, lq'=2(lq&1)+(t>>1)), source mi =
// 2ks+(lq>>1), source word = t&1 -- movement is across lq only (lane +-16/32).
// With A0=pk(word0,mi=2ks), A1=pk(word1,mi=2ks), B0/B1 same for mi=2ks+1:
//   permlane32_swap(A0,B0); permlane16_swap(A0,B0)  ->  A0=[t0], B0=[t2]
//   permlane32_swap(A1,B1); permlane16_swap(A1,B1)  ->  A1=[t1], B1=[t3]
// (permlane32: D=[D.lo|S.lo], S=[D.hi|S.hi] -- validated on HW in R13;
//  permlane16: D=[Dr0,Sr0,Dr2,Sr2], S=[Dr1,Sr1,Dr3,Sr3].)
// pf = (A0,A1,B0,B1). LDS ops/iter 28 -> 16; all 8 MFMA chains and the R7
// staging/vmcnt(4) schedule unchanged. pf single-buffered: PV(k) reads pf
// before expP overwrites it with P(k+1) in program order.
__global__ __launch_bounds__(256, 2) void attn_kernel(
    const ushort* __restrict__ Q, const ushort* __restrict__ Km,
    const ushort* __restrict__ Vt, ushort* __restrict__ ctx) {
    const int bid = blockIdx.x;
    const int xcd = bid & 7, lb = bid >> 3;
    const int bh = xcd * 4 + (lb & 3);
    const int qt = lb >> 2;
    const int q0 = qt * 128;
    __shared__ __align__(16) ushort sK[3][64 * 64];   // 24 KB
    __shared__ __align__(16) ushort sV[3][64 * 64];   // 24 KB
    __shared__ __align__(16) ushort sQ[4][32 * 64];   // 16 KB (Q only)
    const int tid = threadIdx.x;
    const int wave = tid >> 6, lane = tid & 63;
    const int lr = lane & 15, lq = lane >> 4;
    const int srow = lane >> 3, sp = lane & 7;
    const ushort* Qh = Q + (size_t)bh * S_LEN * DK;
    const ushort* Kh = Km + (size_t)bh * S_LEN * DK;
    const ushort* Vh = Vt + (size_t)bh * DK * S_LEN;
    ushort* sQw = sQ[wave];

    // stage this wave's 32 Q rows (swizzled chunks, DMA-linear dest)
#pragma unroll
    for (int t = 0; t < 4; t++) {
        int row = t * 8 + srow;
        int c = sp ^ (row & 7);
        async16(&Qh[(size_t)(q0 + wave * 32 + row) * DK + c * 8],
                &sQw[t * 8 * 64]);
    }

    auto stageK = [&](int k0, int buf) {
#pragma unroll
        for (int t = 0; t < 2; t++) {
            int row = wave * 16 + t * 8 + srow;
            int c = sp ^ (row & 7);
            async16(&Kh[(size_t)(k0 + row) * DK + c * 8],
                    &sK[buf][(wave * 16 + t * 8) * 64]);
        }
    };
    auto stageV = [&](int k0, int buf) {
#pragma unroll
        for (int t = 0; t < 2; t++) {
            int row = wave * 16 + t * 8 + srow;
            int c = sp ^ (row & 7);
            async16(&Vh[(size_t)row * S_LEN + k0 + c * 8],
                    &sV[buf][(wave * 16 + t * 8) * 64]);
        }
    };

    // prologue stages: K(0..2), V(0..1)
    stageK(0, 0);
    stageV(0, 0);
    stageK(64, 1);
    stageV(64, 1);
    stageK(128, 2);
    __syncthreads();                     // drains all DMA (full vmcnt(0))

    bf16x8 qf[2][2];
#pragma unroll
    for (int nj = 0; nj < 2; nj++)
#pragma unroll
        for (int kk = 0; kk < 2; kk++)
            qf[nj][kk] = ldfrag(&sQw[(nj * 16 + lr) * 64 +
                                     (((kk * 4 + lq) ^ (lr & 7)) * 8)]);

    union { uint4 u; bf16x8 b; } one_u;
    one_u.u = make_uint4(0x3F803F80u, 0x3F803F80u, 0x3F803F80u, 0x3F803F80u);
    const bf16x8 ones = one_u.b;

    f32x4 cacc[2][4] = {};
    f32x4 ssum[2] = {};
    bf16x8 pf00, pf01, pf10, pf11;       // [ks][nj] PV A-fragments (registers)

    // S^T = K * Q^T : lane holds P[k=mi*16+lq*4+r][q=lr], nj picks q half
    auto qk = [&](const ushort* sk, f32x4 (*sacc)[2]) {
#pragma unroll
        for (int kk = 0; kk < 2; kk++) {
            bf16x8 kf[4];
            int swz = ((kk * 4 + lq) ^ (lr & 7)) * 8;
#pragma unroll
            for (int mi = 0; mi < 4; mi++)
                kf[mi] = ldfrag(&sk[(mi * 16 + lr) * 64 + swz]);
            __builtin_amdgcn_s_setprio(1);
#pragma unroll
            for (int mi = 0; mi < 4; mi++)
#pragma unroll
                for (int nj = 0; nj < 2; nj++)
                    sacc[mi][nj] = __builtin_amdgcn_mfma_f32_16x16x32_bf16(
                        kf[mi], qf[nj][kk], sacc[mi][nj], 0, 0, 0);
            __builtin_amdgcn_s_setprio(0);
        }
    };

    // P = exp2(S^T) -> PV bf16 A-fragments, fully in-register
    auto expP = [&](f32x4 (*sacc)[2]) {
#pragma unroll
        for (int ks = 0; ks < 2; ks++)
#pragma unroll
            for (int nj = 0; nj < 2; nj++) {
                float a0 = fast_exp2(sacc[2 * ks][nj][0]);
                float a1 = fast_exp2(sacc[2 * ks][nj][1]);
                float a2 = fast_exp2(sacc[2 * ks][nj][2]);
                float a3 = fast_exp2(sacc[2 * ks][nj][3]);
                float b0 = fast_exp2(sacc[2 * ks + 1][nj][0]);
                float b1 = fast_exp2(sacc[2 * ks + 1][nj][1]);
                float b2 = fast_exp2(sacc[2 * ks + 1][nj][2]);
                float b3 = fast_exp2(sacc[2 * ks + 1][nj][3]);
                uint32_t A0 = packbf_rn(a0, a1);
                uint32_t A1 = packbf_rn(a2, a3);
                uint32_t B0 = packbf_rn(b0, b1);
                uint32_t B1 = packbf_rn(b2, b3);
                asm("v_permlane32_swap_b32 %0, %1" : "+v"(A0), "+v"(B0));
                asm("v_permlane16_swap_b32 %0, %1" : "+v"(A0), "+v"(B0));
                asm("v_permlane32_swap_b32 %0, %1" : "+v"(A1), "+v"(B1));
                asm("v_permlane16_swap_b32 %0, %1" : "+v"(A1), "+v"(B1));
                union { uint4 u; bf16x8 b; } cv;
                cv.u = make_uint4(A0, A1, B0, B1);
                if (ks == 0) { if (nj == 0) pf00 = cv.b; else pf01 = cv.b; }
                else         { if (nj == 0) pf10 = cv.b; else pf11 = cv.b; }
            }
    };

    // ctx += P * V^T ; ssum += P * 1   (pf from registers; only vf from LDS)
    auto pv = [&](const ushort* sv) {
#pragma unroll
        for (int ks = 0; ks < 2; ks++) {
            bf16x8 vf[4];
            int swz = ((ks * 4 + lq) ^ (lr & 7)) * 8;
#pragma unroll
            for (int nd = 0; nd < 4; nd++)
                vf[nd] = ldfrag(&sv[(nd * 16 + lr) * 64 + swz]);
            bf16x8 p0 = ks ? pf10 : pf00;
            bf16x8 p1 = ks ? pf11 : pf01;
            __builtin_amdgcn_s_setprio(1);
#pragma unroll
            for (int nd = 0; nd < 4; nd++) {
                cacc[0][nd] = __builtin_amdgcn_mfma_f32_16x16x32_bf16(
                    p0, vf[nd], cacc[0][nd], 0, 0, 0);
                cacc[1][nd] = __builtin_amdgcn_mfma_f32_16x16x32_bf16(
                    p1, vf[nd], cacc[1][nd], 0, 0, 0);
            }
            ssum[0] = __builtin_amdgcn_mfma_f32_16x16x32_bf16(
                p0, ones, ssum[0], 0, 0, 0);
            ssum[1] = __builtin_amdgcn_mfma_f32_16x16x32_bf16(
                p1, ones, ssum[1], 0, 0, 0);
            __builtin_amdgcn_s_setprio(0);
        }
    };

    {   // prologue: QK(0) -> P(0) fragments
        f32x4 s0[4][2] = {};
        qk(sK[0], s0);
        expP(s0);
    }
    // protect sK[0] from iter-0's stageK(3) (3%3=0): all waves' prologue K0
    // reads are register-complete before each wave reaches this barrier.
    __builtin_amdgcn_s_barrier();

#pragma unroll 3
    for (int k = 0; k < 31; k++) {
        if (k + 3 < 32) stageK((k + 3) * 64, (k + 3) % 3);
        if (k + 2 < 32) stageV((k + 2) * 64, (k + 2) % 3);
        f32x4 s2[4][2] = {};
        qk(sK[(k + 1) % 3], s2);         // QK(k+1): staged 2 iters ago
        pv(sV[k % 3]);                   // PV(k): pf = P(k), V(k)
        if (k < 29) pipe_barrier<4>();   // this iter's 4 DMA stay in flight
        else if (k == 29) pipe_barrier<2>();
        else pipe_barrier<0>();
        expP(s2);                        // pf = P(k+1); overlaps next QK
    }
    pv(sV[31 % 3]);                      // PV(31)

    const int b = bh >> 4, h = bh & 15;
    float inv[2][4];
#pragma unroll
    for (int nj = 0; nj < 2; nj++)
#pragma unroll
        for (int r = 0; r < 4; r++)
            inv[nj][r] = __builtin_amdgcn_rcpf(ssum[nj][r]);
#pragma unroll
    for (int nj = 0; nj < 2; nj++)
#pragma unroll
        for (int nd = 0; nd < 4; nd++)
#pragma unroll
            for (int r = 0; r < 4; r++) {
                int qrow = q0 + wave * 32 + nj * 16 + lq * 4 + r;
                int d = nd * 16 + lr;
                float v = cacc[nj][nd][r] * inv[nj][r];
                ctx[(size_t)(b * S_LEN + qrow) * D_MODEL + h * DK + d] = f2bf(v);
            }
}

// ---------------- launch ----------------

extern "C" void kernel_launch(void* const* d_in, const int* in_sizes, int n_in,
                              void* d_out, int out_size, void* d_ws, size_t ws_size,
                              hipStream_t stream) {
    const float* x  = (const float*)d_in[0];
    const float* Wq = (const float*)d_in[1];
    const float* bq = (const float*)d_in[2];
    const float* Wk = (const float*)d_in[3];
    const float* bk = (const float*)d_in[4];
    const float* Wv = (const float*)d_in[5];
    const float* bv = (const float*)d_in[6];
    const float* Wo = (const float*)d_in[7];
    const float* bo = (const float*)d_in[8];

    char* ws = (char*)d_ws;
    ushort* xb    = (ushort*)(ws);                        // 8 MB
    ushort* wqkv  = (ushort*)(ws + (8ull  << 20));        // 6 MB (B^T)
    ushort* wo_t  = (ushort*)(ws + (14ull << 20));        // 2 MB (B^T)
    ushort* qbuf  = (ushort*)(ws + (16ull << 20));        // 8 MB [32][2048][64]
    ushort* kbuf  = (ushort*)(ws + (24ull << 20));        // 8 MB [32][2048][64]
    ushort* vtb   = (ushort*)(ws + (32ull << 20));        // 8 MB [32][64][2048]
    ushort* ctx   = (ushort*)(ws + (40ull << 20));        // 8 MB [4096][1024]
    float*  biasq = (float*)(ws + (48ull << 20));         // 12 KB [3072]

    cvt_fused_kernel<<<8204, 256, 0, stream>>>(
        x, xb, Wq, Wk, Wv, Wo,
        wqkv, wqkv + 1024 * 1024, wqkv + 2 * 1024 * 1024, wo_t,
        bq, bk, bv, biasq);

    gemm_kernel<0><<<768, 256, 0, stream>>>(
        xb, wqkv, biasq, qbuf, kbuf, vtb, nullptr, nullptr);
    attn_kernel<<<512, 256, 0, stream>>>(qbuf, kbuf, vtb, ctx);
    gemm_kernel<1><<<512, 256, 0, stream>>>(
        ctx, wo_t, bo, nullptr, nullptr, nullptr, x, (float*)d_out);
}